// Round 1
// baseline (142.873 us; speedup 1.0000x reference)
//
#include <hip/hip_runtime.h>

// DynamicWeights fused kernel, fp32 vector path.
// x: (8,64,192,192) f32, conv_w: (9,64,3,3) f32, gamma: (1,) f32
// out = gamma * einsum(patches3x3(x), softmax(conv3x3(x, conv_w), k)) + x

constexpr int Nn = 8, Cc = 64, Hh = 192, Ww = 192;
constexpr int TW = 64, TH = 4;      // spatial tile per block (256 threads, 1 px/thread)
constexpr int CCH = 4;              // channels staged in LDS per chunk
constexpr int LW = TW + 2;          // 66 (halo)
constexpr int LH = TH + 2;          // 6  (halo)

__global__ __launch_bounds__(256)
void dynw_fused(const float* __restrict__ x, const float* __restrict__ cw,
                const float* __restrict__ gamma, float* __restrict__ out)
{
    __shared__ float xs[CCH][LH][LW];

    const int tx = threadIdx.x & 63;
    const int ty = threadIdx.x >> 6;
    const int w0 = blockIdx.x * TW;
    const int h0 = blockIdx.y * TH;
    const int n  = blockIdx.z;
    const int h  = h0 + ty;
    const int w  = w0 + tx;

    const float* xn = x + (size_t)n * Cc * Hh * Ww;

    float dyn[9];
#pragma unroll
    for (int k = 0; k < 9; ++k) dyn[k] = 0.f;

    // ---- Phase A: conv -> dyn[9] per pixel ----
    for (int c0 = 0; c0 < Cc; c0 += CCH) {
        __syncthreads();
        for (int idx = threadIdx.x; idx < CCH * LH * LW; idx += 256) {
            int col = idx % LW;
            int rr  = idx / LW;
            int r   = rr % LH;
            int cc  = rr / LH;
            int gh  = h0 + r - 1;
            int gw  = w0 + col - 1;
            float v = 0.f;
            if ((unsigned)gh < (unsigned)Hh && (unsigned)gw < (unsigned)Ww)
                v = xn[((size_t)(c0 + cc) * Hh + gh) * Ww + gw];
            xs[cc][r][col] = v;
        }
        __syncthreads();
#pragma unroll
        for (int cc = 0; cc < CCH; ++cc) {
            const int c = c0 + cc;
            float xv[9];
#pragma unroll
            for (int di = 0; di < 3; ++di)
#pragma unroll
                for (int dj = 0; dj < 3; ++dj)
                    xv[di * 3 + dj] = xs[cc][ty + di][tx + dj];
            // weights: index is wave-uniform (c uniform, k/p unrolled consts)
            const float* wc = cw + c * 9;
#pragma unroll
            for (int k = 0; k < 9; ++k) {
                const float* wk = wc + (size_t)k * Cc * 9;
#pragma unroll
                for (int p = 0; p < 9; ++p)
                    dyn[k] = fmaf(xv[p], wk[p], dyn[k]);
            }
        }
    }

    // ---- softmax over the 9 taps (thread-local) ----
    float m = dyn[0];
#pragma unroll
    for (int k = 1; k < 9; ++k) m = fmaxf(m, dyn[k]);
    float f[9];
    float s = 0.f;
#pragma unroll
    for (int k = 0; k < 9; ++k) { f[k] = __expf(dyn[k] - m); s += f[k]; }
    const float inv = 1.0f / s;
#pragma unroll
    for (int k = 0; k < 9; ++k) f[k] *= inv;

    const float g = gamma[0];
    float* outn = out + (size_t)n * Cc * Hh * Ww;

    // ---- Phase B: weighted 3x3 combine + residual ----
    for (int c0 = 0; c0 < Cc; c0 += CCH) {
        __syncthreads();
        for (int idx = threadIdx.x; idx < CCH * LH * LW; idx += 256) {
            int col = idx % LW;
            int rr  = idx / LW;
            int r   = rr % LH;
            int cc  = rr / LH;
            int gh  = h0 + r - 1;
            int gw  = w0 + col - 1;
            float v = 0.f;
            if ((unsigned)gh < (unsigned)Hh && (unsigned)gw < (unsigned)Ww)
                v = xn[((size_t)(c0 + cc) * Hh + gh) * Ww + gw];
            xs[cc][r][col] = v;
        }
        __syncthreads();
#pragma unroll
        for (int cc = 0; cc < CCH; ++cc) {
            const int c = c0 + cc;
            float acc = 0.f;
#pragma unroll
            for (int di = 0; di < 3; ++di)
#pragma unroll
                for (int dj = 0; dj < 3; ++dj)
                    acc = fmaf(xs[cc][ty + di][tx + dj], f[di * 3 + dj], acc);
            const float xc = xs[cc][ty + 1][tx + 1];
            outn[((size_t)c * Hh + h) * Ww + w] = fmaf(g, acc, xc);
        }
    }
}

extern "C" void kernel_launch(void* const* d_in, const int* in_sizes, int n_in,
                              void* d_out, int out_size, void* d_ws, size_t ws_size,
                              hipStream_t stream) {
    const float* x  = (const float*)d_in[0];
    const float* cw = (const float*)d_in[1];
    const float* gm = (const float*)d_in[2];
    float* out = (float*)d_out;

    dim3 grid(Ww / TW, Hh / TH, Nn);   // (3, 48, 8)
    dim3 block(256);
    dynw_fused<<<grid, block, 0, stream>>>(x, cw, gm, out);
}